// Round 3
// baseline (1271.302 us; speedup 1.0000x reference)
//
#include <hip/hip_runtime.h>
#include <stdint.h>

// GPUHausdorffLoss — pipeline (R3):
//  K1 sobel_code (2048 blk x 256): Sobel valid + threefry m ONCE per pixel,
//     straight-line (no per-pixel branches around threefry); writes uint8 coarse
//     bin code (0=invalid, else bin+1, bins = v>>14 clamped to 254) + per-image
//     256-bin histogram + valid count.
//  K2 thresh (128 blk): suffix-scan 256-bin hist -> threshold bin T, r, need.
//  K3 collect (2048 blk): byte-scan codes (uint4 = 16 px/thread/iter); bin>T emit
//     point, bin==T emit candidate pixel index. No threefry.
//  K4 resolve (128 blk): recompute m for ~900 candidates, exact (m desc, idx asc)
//     rank, take r. Center fallback when no valid pixels.
//  K5 haus (512 blk): per (img, dir, quarter) partial max of min d^2, atomicMax.
//  K6 finalize: clip(sqrt/diag), mean.

#define HH 512
#define WW 512
#define NPIX (HH * WW)
#define NSEL 1000
#define NBIN 256
#define CANDCAP 4096
#define ROWS_PER 32
#define SLICES 16

#if __has_builtin(__builtin_amdgcn_alignbit)
__device__ __forceinline__ uint32_t rotl32(uint32_t x, int r) {
  return __builtin_amdgcn_alignbit(x, x, (32 - r) & 31);  // v_alignbit rotate
}
#else
__device__ __forceinline__ uint32_t rotl32(uint32_t x, int r) {
  return (x << r) | (x >> (32 - r));
}
#endif

// JAX threefry2x32: 20 rounds, key schedule every 4.
__device__ __forceinline__ void tf2x32(uint32_t k0, uint32_t k1,
                                       uint32_t c0, uint32_t c1,
                                       uint32_t& o0, uint32_t& o1) {
  uint32_t ks2 = k0 ^ k1 ^ 0x1BD11BDAu;
  uint32_t x0 = c0 + k0, x1 = c1 + k1;
#define TF_R(r) { x0 += x1; x1 = rotl32(x1, (r)); x1 ^= x0; }
  TF_R(13) TF_R(15) TF_R(26) TF_R(6)
  x0 += k1;  x1 += ks2 + 1u;
  TF_R(17) TF_R(29) TF_R(16) TF_R(24)
  x0 += ks2; x1 += k0 + 2u;
  TF_R(13) TF_R(15) TF_R(26) TF_R(6)
  x0 += k0;  x1 += k1 + 3u;
  TF_R(17) TF_R(29) TF_R(16) TF_R(24)
  x0 += k1;  x1 += ks2 + 4u;
  TF_R(13) TF_R(15) TF_R(26) TF_R(6)
  x0 += ks2; x1 += k0 + 5u;
#undef TF_R
  o0 = x0; o1 = x1;
}

// Exact rank value of score = 2.0f + uniform(bits): bits(score) - bits(2.0f).
__device__ __forceinline__ uint32_t pixel_m(uint32_t k0, uint32_t k1, int p) {
  uint32_t b1, b2;
  tf2x32(k0, k1, 0u, (uint32_t)p, b1, b2);
  uint32_t bits = b1 ^ b2;
  float noise = __uint_as_float((bits >> 9) | 0x3F800000u) - 1.0f;
  float score = 2.0f + noise;
  return __float_as_uint(score) - 0x40000000u;  // 0 .. 0x400000 inclusive
}

__device__ __forceinline__ float sigf(float x) { return 1.0f / (1.0f + __expf(-x)); }

__device__ __forceinline__ float ldval(const float* __restrict__ img, int r, int c, bool isPred) {
  if (r < 0 || r > HH - 1 || c < 0 || c > WW - 1) return 0.0f;  // conv zero-pad (post-sigmoid)
  float v = img[r * WW + c];
  return isPred ? sigf(v) : v;
}

// ---------------- K1 ----------------
__global__ __launch_bounds__(256) void sobel_code(
    const float* __restrict__ pred, const float* __restrict__ tgt,
    int* __restrict__ g_hist, int* __restrict__ g_cv, uint16_t* __restrict__ g_code) {
  const int bid = blockIdx.x;
  const int b = bid >> 4, s = bid & 15;
  const int r0 = s * ROWS_PER;
  const int t = threadIdx.x;
  const bool isPred = b < 64;
  const float* img = isPred ? pred + (size_t)b * NPIX : tgt + (size_t)(b - 64) * NPIX;

  __shared__ int hist[NBIN];
  __shared__ int s_cv;
  hist[t] = 0;
  if (t == 0) s_cv = 0;
  __syncthreads();

  uint32_t k0, k1;
  tf2x32(0u, 1u, 0u, (uint32_t)b, k0, k1);

  const int c0 = 2 * t;
  float a0 = ldval(img, r0 - 1, c0 - 1, isPred), a1 = ldval(img, r0 - 1, c0, isPred),
        a2 = ldval(img, r0 - 1, c0 + 1, isPred), a3 = ldval(img, r0 - 1, c0 + 2, isPred);
  float b0 = ldval(img, r0, c0 - 1, isPred), b1 = ldval(img, r0, c0, isPred),
        b2 = ldval(img, r0, c0 + 1, isPred), b3 = ldval(img, r0, c0 + 2, isPred);
  float d0 = ldval(img, r0 + 1, c0 - 1, isPred), d1 = ldval(img, r0 + 1, c0, isPred),
        d2 = ldval(img, r0 + 1, c0 + 1, isPred), d3 = ldval(img, r0 + 1, c0 + 2, isPred);

  int cnt = 0;
  uint16_t* dst = g_code + ((size_t)b * NPIX >> 1) + t;  // row stride 256 (u16 units)
  for (int rr = 0; rr < ROWS_PER; ++rr) {
    const int r = r0 + rr;
    const int p = r * WW + c0;
    // Sobel both pixels (straight-line)
    float gx0 = (a2 - a0) + 2.0f * (b2 - b0) + (d2 - d0);
    float gy0 = (d0 - a0) + 2.0f * (d1 - a1) + (d2 - a2);
    float gx1 = (a3 - a1) + 2.0f * (b3 - b1) + (d3 - d1);
    float gy1 = (d1 - a1) + 2.0f * (d2 - a2) + (d3 - a3);
    bool v0 = sqrtf(gx0 * gx0 + gy0 * gy0 + 1e-8f) > 0.1f;
    bool v1 = sqrtf(gx1 * gx1 + gy1 * gy1 + 1e-8f) > 0.1f;
    // threefry unconditionally (two independent chains -> ILP)
    uint32_t m0 = pixel_m(k0, k1, p);
    uint32_t m1 = pixel_m(k0, k1, p + 1);
    uint32_t val0 = v0 ? m0 + 1u : 0u;
    uint32_t val1 = v1 ? m1 + 1u : 0u;
    uint32_t bin0 = val0 >> 14; if (bin0 > 254u) bin0 = 254u;
    uint32_t bin1 = val1 >> 14; if (bin1 > 254u) bin1 = 254u;
    uint32_t code0 = v0 ? bin0 + 1u : 0u;
    uint32_t code1 = v1 ? bin1 + 1u : 0u;
    if (v0) atomicAdd(&hist[bin0], 1);
    if (v1) atomicAdd(&hist[bin1], 1);
    cnt += (int)v0 + (int)v1;
    dst[(size_t)r * 256] = (uint16_t)(code0 | (code1 << 8));
    if (rr < ROWS_PER - 1) {
      a0 = b0; a1 = b1; a2 = b2; a3 = b3;
      b0 = d0; b1 = d1; b2 = d2; b3 = d3;
      d0 = ldval(img, r + 2, c0 - 1, isPred);
      d1 = ldval(img, r + 2, c0, isPred);
      d2 = ldval(img, r + 2, c0 + 1, isPred);
      d3 = ldval(img, r + 2, c0 + 2, isPred);
    }
  }
  atomicAdd(&s_cv, cnt);
  __syncthreads();
  if (t == 0) atomicAdd(&g_cv[b], s_cv);
  int h = hist[t];
  if (h) atomicAdd(&g_hist[b * NBIN + t], h);
}

// ---------------- K2 ----------------
__global__ __launch_bounds__(256) void thresh_kernel(
    const int* __restrict__ g_hist, const int* __restrict__ g_cv,
    int* __restrict__ g_params) {
  const int img = blockIdx.x;
  const int t = threadIdx.x;
  __shared__ int sfx[NBIN];
  const int cv = g_cv[img];
  int* params = g_params + img * 4;
  if (cv == 0) {
    if (t == 0) { params[0] = 1; params[1] = -1; params[2] = 0; params[3] = 0; }
    return;
  }
  const int need = cv < NSEL ? cv : NSEL;
  sfx[t] = g_hist[img * NBIN + t];
  __syncthreads();
  for (int o = 1; o < NBIN; o <<= 1) {  // Hillis-Steele inclusive suffix sum
    int v = (t + o < NBIN) ? sfx[t + o] : 0;
    __syncthreads();
    sfx[t] += v;
    __syncthreads();
  }
  int nxt = (t + 1 < NBIN) ? sfx[t + 1] : 0;
  if (sfx[t] >= need && nxt < need) {
    params[0] = 0;
    params[1] = t;          // threshold bin T
    params[2] = need - nxt; // r from bin T
    params[3] = nxt;        // strictly above
  }
}

// ---------------- K3 ----------------
__global__ __launch_bounds__(256) void collect_kernel(
    const uint8_t* __restrict__ g_code, const int* __restrict__ g_params,
    int* __restrict__ g_counts, uint32_t* __restrict__ g_pts,
    int* __restrict__ g_candc, uint32_t* __restrict__ g_cand) {
  const int bid = blockIdx.x;
  const int b = bid >> 4, s = bid & 15;
  const int t = threadIdx.x;
  if (g_params[b * 4 + 0]) return;  // cv==0
  const uint32_t T = (uint32_t)g_params[b * 4 + 1];
  const int base = s * (ROWS_PER * WW);  // local pixel base
  const uint4* src = (const uint4*)(g_code + (size_t)b * NPIX + base);
  for (int it = 0; it < 4; ++it) {
    const int idx = it * 256 + t;
    uint4 w = src[idx];
    const int pbase = base + idx * 16;
    uint32_t words[4] = {w.x, w.y, w.z, w.w};
#pragma unroll
    for (int wi = 0; wi < 4; ++wi) {
      uint32_t word = words[wi];
#pragma unroll
      for (int j = 0; j < 4; ++j) {
        uint32_t c = (word >> (8 * j)) & 0xFFu;
        if (c == 0u) continue;
        uint32_t bin = c - 1u;
        if (bin > T) {
          int pos = atomicAdd(&g_counts[b], 1);
          int p = pbase + wi * 4 + j;
          g_pts[b * NSEL + pos] = ((uint32_t)(p >> 9) << 16) | (uint32_t)(p & 511);
        } else if (bin == T) {
          int cp = atomicAdd(&g_candc[b], 1);
          if (cp < CANDCAP) g_cand[(size_t)b * CANDCAP + cp] = (uint32_t)(pbase + wi * 4 + j);
        }
      }
    }
  }
}

// ---------------- K4 ----------------
__global__ __launch_bounds__(256) void resolve_kernel(
    const int* __restrict__ g_params, int* __restrict__ g_counts,
    uint32_t* __restrict__ g_pts, const int* __restrict__ g_candc,
    const uint32_t* __restrict__ g_cand) {
  const int img = blockIdx.x;
  const int t = threadIdx.x;
  if (g_params[img * 4 + 0]) {  // cv==0 -> center fallback
    if (t == 0) { g_pts[img * NSEL] = (256u << 16) | 256u; g_counts[img] = 1; }
    return;
  }
  const int rneed = g_params[img * 4 + 2];
  int nc = g_candc[img]; if (nc > CANDCAP) nc = CANDCAP;
  __shared__ uint32_t sp[CANDCAP];
  __shared__ uint32_t sm[CANDCAP];
  uint32_t k0, k1;
  tf2x32(0u, 1u, 0u, (uint32_t)img, k0, k1);
  for (int i = t; i < nc; i += 256) {
    uint32_t p = g_cand[(size_t)img * CANDCAP + i];
    sp[i] = p;
    sm[i] = pixel_m(k0, k1, (int)p);
  }
  __syncthreads();
  for (int i = t; i < nc; i += 256) {
    uint32_t mi = sm[i], pi = sp[i];
    int rank = 0;
    for (int j = 0; j < nc; ++j) {
      uint32_t mj = sm[j];
      rank += (mj > mi) || (mj == mi && sp[j] < pi);
    }
    if (rank < rneed) {
      int pos = atomicAdd(&g_counts[img], 1);
      g_pts[img * NSEL + pos] = ((pi >> 9) << 16) | (pi & 511u);
    }
  }
}

// ---------------- K5 ----------------
__global__ __launch_bounds__(256) void haus_kernel(
    const uint32_t* __restrict__ g_pts, const int* __restrict__ g_counts,
    float* __restrict__ g_maxd2) {
  const int bid = blockIdx.x;
  const int img = bid >> 3;
  const int dir = (bid >> 2) & 1;
  const int seg = bid & 3;
  const int t = threadIdx.x;
  const int iOwn = dir ? 64 + img : img;
  const int iOth = dir ? img : 64 + img;
  const int nOwn = g_counts[iOwn];
  const int nOth = g_counts[iOth];
  __shared__ float2 o[NSEL];
  __shared__ float red[256];
  for (int i = t; i < nOth; i += 256) {
    uint32_t v = g_pts[iOth * NSEL + i];
    o[i] = make_float2((float)(v >> 16), (float)(v & 0xFFFFu));
  }
  __syncthreads();
  float best = 0.0f;  // d^2 >= 0
  const int lo = seg * 250;
  const int hi = min(nOwn, lo + 250);
  for (int i = lo + t; i < hi; i += 256) {
    uint32_t v = g_pts[iOwn * NSEL + i];
    float pr = (float)(v >> 16), pc = (float)(v & 0xFFFFu);
    float mn = 3.4e38f;
    for (int j = 0; j < nOth; ++j) {
      float dr = pr - o[j].x, dc = pc - o[j].y;
      mn = fminf(mn, dr * dr + dc * dc);
    }
    best = fmaxf(best, mn);
  }
  red[t] = best;
  __syncthreads();
  for (int st = 128; st > 0; st >>= 1) {
    if (t < st) red[t] = fmaxf(red[t], red[t + st]);
    __syncthreads();
  }
  if (t == 0) atomicMax((unsigned int*)&g_maxd2[img], __float_as_uint(red[0]));
}

// ---------------- K6 ----------------
__global__ __launch_bounds__(64) void fin_kernel(const float* __restrict__ g_maxd2,
                                                 float* __restrict__ out) {
  const int t = threadIdx.x;
  float diag = sqrtf((float)(HH * HH + WW * WW));
  float hd = sqrtf(fmaxf(g_maxd2[t], 0.0f)) / diag;
  hd = fminf(fmaxf(hd, 0.0f), 0.1f);
  float s = hd;
  for (int o = 32; o > 0; o >>= 1) s += __shfl_down(s, o);
  if (t == 0) out[0] = s * 0.015625f;
}

// ---------------- workspace layout (bytes) ----------------
#define WS_HIST   0u                        // 128*256*4 = 131072
#define WS_CV     131072u                   // 512
#define WS_COUNTS (WS_CV + 512u)            // 512
#define WS_CANDC  (WS_COUNTS + 512u)        // 512
#define WS_MAXD2  (WS_CANDC + 512u)         // 256
#define WS_PARAMS (WS_MAXD2 + 256u)         // 2048
#define WS_ZEND   (WS_PARAMS + 2048u)       // zero through here = 134912
#define WS_PTS    WS_ZEND                   // 128*1000*4 = 512000
#define WS_CAND   (WS_PTS + 512000u)        // 128*4096*4 = 2097152
#define WS_CODE   (WS_CAND + 2097152u)      // 128*262144*1 = 33554432 (~36.3 MB total)

extern "C" void kernel_launch(void* const* d_in, const int* in_sizes, int n_in,
                              void* d_out, int out_size, void* d_ws, size_t ws_size,
                              hipStream_t stream) {
  const float* pred = (const float*)d_in[0];
  const float* tgt = (const float*)d_in[1];
  float* out = (float*)d_out;
  char* ws = (char*)d_ws;
  int* g_hist = (int*)(ws + WS_HIST);
  int* g_cv = (int*)(ws + WS_CV);
  int* g_counts = (int*)(ws + WS_COUNTS);
  int* g_candc = (int*)(ws + WS_CANDC);
  float* g_maxd2 = (float*)(ws + WS_MAXD2);
  int* g_params = (int*)(ws + WS_PARAMS);
  uint32_t* g_pts = (uint32_t*)(ws + WS_PTS);
  uint32_t* g_cand = (uint32_t*)(ws + WS_CAND);
  uint16_t* g_code16 = (uint16_t*)(ws + WS_CODE);
  const uint8_t* g_code8 = (const uint8_t*)(ws + WS_CODE);

  hipMemsetAsync(d_out, 0, (size_t)out_size * sizeof(float), stream);
  hipMemsetAsync(d_ws, 0, WS_ZEND, stream);
  sobel_code<<<128 * SLICES, 256, 0, stream>>>(pred, tgt, g_hist, g_cv, g_code16);
  thresh_kernel<<<128, 256, 0, stream>>>(g_hist, g_cv, g_params);
  collect_kernel<<<128 * SLICES, 256, 0, stream>>>(g_code8, g_params, g_counts, g_pts, g_candc, g_cand);
  resolve_kernel<<<128, 256, 0, stream>>>(g_params, g_counts, g_pts, g_candc, g_cand);
  haus_kernel<<<512, 256, 0, stream>>>(g_pts, g_counts, g_maxd2);
  fin_kernel<<<1, 64, 0, stream>>>(g_maxd2, out);
}

// Round 4
// 315.940 us; speedup vs baseline: 4.0239x; 4.0239x over previous
//
#include <hip/hip_runtime.h>
#include <stdint.h>

// GPUHausdorffLoss — pipeline (R4): no code array, no collect pass, no contended
// return-value global atomics.
//  K1 sobel_cand (2048 blk): Sobel + threefry once/px; per-image 256-bin hist
//     (fire-and-forget atomics); candidates (m,p) for coarse bin >= 252 staged in
//     LDS, one reservation atomic per block.
//  K2 thresh (128 blk): suffix-scan hist -> exact T, r; repair flag if candidates
//     can't cover (T<252 or overflow) — unreachable for this input but exact.
//  K3 repair (2048 blk): early-exit unless flag; rebuilds candidates with bin>=T.
//  K4 resolve (128 blk, 1 blk/img): direct-emit bin>T; fine 1024-bin radix within
//     bin==T; exact (m desc, idx asc) rank on residual ties. LDS position counter,
//     single count store.
//  K5 haus (512 blk): per (img,dir,half) partial max of min d^2, atomicMax.
//  K6 fin.

#define HH 512
#define WW 512
#define NPIX (HH * WW)
#define NSEL 1000
#define NBIN 256
#define CBIN_CUT 252u
#define CANDCAP 16384
#define STAGECAP 2048
#define ROWS_PER 32

#if __has_builtin(__builtin_amdgcn_alignbit)
__device__ __forceinline__ uint32_t rotl32(uint32_t x, int r) {
  return __builtin_amdgcn_alignbit(x, x, (32 - r) & 31);
}
#else
__device__ __forceinline__ uint32_t rotl32(uint32_t x, int r) {
  return (x << r) | (x >> (32 - r));
}
#endif

// JAX threefry2x32: 20 rounds, key schedule every 4.
__device__ __forceinline__ void tf2x32(uint32_t k0, uint32_t k1,
                                       uint32_t c0, uint32_t c1,
                                       uint32_t& o0, uint32_t& o1) {
  uint32_t ks2 = k0 ^ k1 ^ 0x1BD11BDAu;
  uint32_t x0 = c0 + k0, x1 = c1 + k1;
#define TF_R(r) { x0 += x1; x1 = rotl32(x1, (r)); x1 ^= x0; }
  TF_R(13) TF_R(15) TF_R(26) TF_R(6)
  x0 += k1;  x1 += ks2 + 1u;
  TF_R(17) TF_R(29) TF_R(16) TF_R(24)
  x0 += ks2; x1 += k0 + 2u;
  TF_R(13) TF_R(15) TF_R(26) TF_R(6)
  x0 += k0;  x1 += k1 + 3u;
  TF_R(17) TF_R(29) TF_R(16) TF_R(24)
  x0 += k1;  x1 += ks2 + 4u;
  TF_R(13) TF_R(15) TF_R(26) TF_R(6)
  x0 += ks2; x1 += k0 + 5u;
#undef TF_R
  o0 = x0; o1 = x1;
}

// Exact rank value of score = 2.0f + uniform(bits): bits(score) - bits(2.0f).
// m in [0, 0x400000] inclusive (noise can round up to 1.0).
__device__ __forceinline__ uint32_t pixel_m(uint32_t k0, uint32_t k1, int p) {
  uint32_t b1, b2;
  tf2x32(k0, k1, 0u, (uint32_t)p, b1, b2);
  uint32_t bits = b1 ^ b2;
  float noise = __uint_as_float((bits >> 9) | 0x3F800000u) - 1.0f;
  float score = 2.0f + noise;
  return __float_as_uint(score) - 0x40000000u;
}

__device__ __forceinline__ uint32_t cbin_of(uint32_t m) {
  uint32_t b = m >> 14;
  return b > 255u ? 255u : b;
}

__device__ __forceinline__ float sigf(float x) { return 1.0f / (1.0f + __expf(-x)); }

__device__ __forceinline__ float ldval(const float* __restrict__ img, int r, int c, bool isPred) {
  if (r < 0 || r > HH - 1 || c < 0 || c > WW - 1) return 0.0f;  // conv zero-pad (post-sigmoid)
  float v = img[r * WW + c];
  return isPred ? sigf(v) : v;
}

__device__ __forceinline__ uint32_t pack_pt(uint32_t p) {
  return ((p >> 9) << 16) | (p & 511u);
}

// Scan one 32-row slice: Sobel validity + threefry m per pixel; stage (m,p) for
// cbin >= binMin into LDS. Optionally histogram all valid pixels.
template <bool DO_HIST>
__device__ void scan_slice(const float* __restrict__ img, bool isPred, int r0, int t,
                           uint32_t k0, uint32_t k1, uint32_t binMin,
                           int* hist, unsigned long long* stage, int* s_cn) {
  const int c0 = 2 * t;
  float a0 = ldval(img, r0 - 1, c0 - 1, isPred), a1 = ldval(img, r0 - 1, c0, isPred),
        a2 = ldval(img, r0 - 1, c0 + 1, isPred), a3 = ldval(img, r0 - 1, c0 + 2, isPred);
  float b0 = ldval(img, r0, c0 - 1, isPred), b1 = ldval(img, r0, c0, isPred),
        b2 = ldval(img, r0, c0 + 1, isPred), b3 = ldval(img, r0, c0 + 2, isPred);
  float d0 = ldval(img, r0 + 1, c0 - 1, isPred), d1 = ldval(img, r0 + 1, c0, isPred),
        d2 = ldval(img, r0 + 1, c0 + 1, isPred), d3 = ldval(img, r0 + 1, c0 + 2, isPred);

  for (int rr = 0; rr < ROWS_PER; ++rr) {
    const int r = r0 + rr;
    const int p = r * WW + c0;
    float gx0 = (a2 - a0) + 2.0f * (b2 - b0) + (d2 - d0);
    float gy0 = (d0 - a0) + 2.0f * (d1 - a1) + (d2 - a2);
    float gx1 = (a3 - a1) + 2.0f * (b3 - b1) + (d3 - d1);
    float gy1 = (d1 - a1) + 2.0f * (d2 - a2) + (d3 - a3);
    bool v0 = (gx0 * gx0 + gy0 * gy0 + 1e-8f) > 0.01f;  // sqrt(x) > 0.1 <=> x > 0.01
    bool v1 = (gx1 * gx1 + gy1 * gy1 + 1e-8f) > 0.01f;
    uint32_t m0 = pixel_m(k0, k1, p);
    uint32_t m1 = pixel_m(k0, k1, p + 1);
    uint32_t bin0 = cbin_of(m0), bin1 = cbin_of(m1);
    if (v0) {
      if (DO_HIST) atomicAdd(&hist[bin0], 1);
      if (bin0 >= binMin) {
        int i = atomicAdd(s_cn, 1);
        if (i < STAGECAP) stage[i] = ((unsigned long long)m0 << 32) | (uint32_t)p;
      }
    }
    if (v1) {
      if (DO_HIST) atomicAdd(&hist[bin1], 1);
      if (bin1 >= binMin) {
        int i = atomicAdd(s_cn, 1);
        if (i < STAGECAP) stage[i] = ((unsigned long long)m1 << 32) | (uint32_t)(p + 1);
      }
    }
    if (rr < ROWS_PER - 1) {
      a0 = b0; a1 = b1; a2 = b2; a3 = b3;
      b0 = d0; b1 = d1; b2 = d2; b3 = d3;
      d0 = ldval(img, r + 2, c0 - 1, isPred);
      d1 = ldval(img, r + 2, c0, isPred);
      d2 = ldval(img, r + 2, c0 + 1, isPred);
      d3 = ldval(img, r + 2, c0 + 2, isPred);
    }
  }
}

// ---------------- K1 ----------------
__global__ __launch_bounds__(256) void sobel_cand(
    const float* __restrict__ pred, const float* __restrict__ tgt,
    int* __restrict__ g_hist, int* __restrict__ g_candc, int* __restrict__ g_ovf,
    unsigned long long* __restrict__ g_cand) {
  const int bid = blockIdx.x;
  const int b = bid >> 4, s = bid & 15;
  const int t = threadIdx.x;
  const bool isPred = b < 64;
  const float* img = isPred ? pred + (size_t)b * NPIX : tgt + (size_t)(b - 64) * NPIX;

  __shared__ int hist[NBIN];
  __shared__ unsigned long long stage[STAGECAP];
  __shared__ int s_cn, s_base, s_ncopy;
  hist[t] = 0;
  if (t == 0) s_cn = 0;
  __syncthreads();

  uint32_t k0, k1;
  tf2x32(0u, 1u, 0u, (uint32_t)b, k0, k1);

  scan_slice<true>(img, isPred, s * ROWS_PER, t, k0, k1, CBIN_CUT, hist, stage, &s_cn);
  __syncthreads();

  if (t == 0) {
    int raw = s_cn;
    int n = raw < STAGECAP ? raw : STAGECAP;
    int base = atomicAdd(&g_candc[b], n);
    if (raw > STAGECAP || base + n > CANDCAP) g_ovf[b] = 1;
    s_base = base;
    s_ncopy = n;
  }
  __syncthreads();
  const int base = s_base, n = s_ncopy;
  for (int i = t; i < n; i += 256) {
    int gi = base + i;
    if (gi < CANDCAP) g_cand[(size_t)b * CANDCAP + gi] = stage[i];
  }
  int h = hist[t];
  if (h) atomicAdd(&g_hist[b * NBIN + t], h);  // no return value -> coalesced/fast
}

// ---------------- K2 ----------------
__global__ __launch_bounds__(256) void thresh_kernel(
    const int* __restrict__ g_hist, const int* __restrict__ g_ovf,
    int* __restrict__ g_candc, int* __restrict__ g_params) {
  const int img = blockIdx.x;
  const int t = threadIdx.x;
  __shared__ int sfx[NBIN];
  int* params = g_params + img * 4;
  sfx[t] = g_hist[img * NBIN + t];
  __syncthreads();
  for (int o = 1; o < NBIN; o <<= 1) {  // inclusive suffix sum
    int v = (t + o < NBIN) ? sfx[t + o] : 0;
    __syncthreads();
    sfx[t] += v;
    __syncthreads();
  }
  const int cv = sfx[0];
  if (cv == 0) {
    if (t == 0) { params[0] = 2; params[1] = -1; params[2] = 0; params[3] = 0; }
    return;
  }
  const int need = cv < NSEL ? cv : NSEL;
  int nxt = (t + 1 < NBIN) ? sfx[t + 1] : 0;
  if (sfx[t] >= need && nxt < need) {
    int T = t;
    int flag = (T < (int)CBIN_CUT || g_ovf[img]) ? 1 : 0;
    params[0] = 0;
    params[1] = T;
    params[2] = need - nxt;  // r >= 1 from bin T
    params[3] = flag;
    if (flag) g_candc[img] = 0;  // repair rebuilds from scratch
  }
}

// ---------------- K3 repair (no-op unless flag) ----------------
__global__ __launch_bounds__(256) void repair_kernel(
    const float* __restrict__ pred, const float* __restrict__ tgt,
    const int* __restrict__ g_params, int* __restrict__ g_candc,
    unsigned long long* __restrict__ g_cand) {
  const int bid = blockIdx.x;
  const int b = bid >> 4, s = bid & 15;
  if (g_params[b * 4 + 3] == 0) return;
  const int t = threadIdx.x;
  const uint32_t T = (uint32_t)g_params[b * 4 + 1];
  const bool isPred = b < 64;
  const float* img = isPred ? pred + (size_t)b * NPIX : tgt + (size_t)(b - 64) * NPIX;
  __shared__ unsigned long long stage[STAGECAP];
  __shared__ int s_cn, s_base, s_ncopy;
  if (t == 0) s_cn = 0;
  __syncthreads();
  uint32_t k0, k1;
  tf2x32(0u, 1u, 0u, (uint32_t)b, k0, k1);
  scan_slice<false>(img, isPred, s * ROWS_PER, t, k0, k1, T, nullptr, stage, &s_cn);
  __syncthreads();
  if (t == 0) {
    int n = s_cn < STAGECAP ? s_cn : STAGECAP;
    s_base = atomicAdd(&g_candc[b], n);
    s_ncopy = n;
  }
  __syncthreads();
  for (int i = t; i < s_ncopy; i += 256) {
    int gi = s_base + i;
    if (gi < CANDCAP) g_cand[(size_t)b * CANDCAP + gi] = stage[i];
  }
}

// ---------------- K4 resolve (1 block per image-side) ----------------
__global__ __launch_bounds__(256) void resolve_kernel(
    const int* __restrict__ g_params, const int* __restrict__ g_candc,
    const unsigned long long* __restrict__ g_cand,
    uint32_t* __restrict__ g_pts, int* __restrict__ g_counts) {
  const int img = blockIdx.x;
  const int t = threadIdx.x;
  const int mode = g_params[img * 4 + 0];
  if (mode == 2) {  // cv==0 -> center fallback
    if (t == 0) { g_pts[img * NSEL] = (256u << 16) | 256u; g_counts[img] = 1; }
    return;
  }
  const uint32_t T = (uint32_t)g_params[img * 4 + 1];
  const int r = g_params[img * 4 + 2];
  int nc = g_candc[img]; if (nc > CANDCAP) nc = CANDCAP;
  const unsigned long long* C = g_cand + (size_t)img * CANDCAP;

  __shared__ int fh[1024];
  __shared__ int aux[256];
  __shared__ unsigned long long ties[256];
  __shared__ int s_pos, s_nt, s_T2, s_r2;
  for (int i = t; i < 1024; i += 256) fh[i] = 0;
  if (t == 0) { s_pos = 0; s_nt = 0; }
  __syncthreads();

  const uint32_t baseM = T << 14;
  // pass 1: direct-emit cbin>T; fine-hist cbin==T
  for (int i = t; i < nc; i += 256) {
    unsigned long long e = C[i];
    uint32_t m = (uint32_t)(e >> 32), p = (uint32_t)e;
    uint32_t cb = cbin_of(m);
    if (cb > T) {
      int pos = atomicAdd(&s_pos, 1);
      g_pts[img * NSEL + pos] = pack_pt(p);
    } else if (cb == T) {
      uint32_t f = (m - baseM) >> 4; if (f > 1023u) f = 1023u;
      atomicAdd(&fh[f], 1);
    }
  }
  __syncthreads();
  // suffix-scan fh[1024]
  {
    int base = 4 * t, s = 0;
    for (int j = 3; j >= 0; --j) { s += fh[base + j]; fh[base + j] = s; }
    aux[t] = s;
    __syncthreads();
    for (int o = 1; o < 256; o <<= 1) {
      int v = (t + o < 256) ? aux[t + o] : 0;
      __syncthreads();
      aux[t] += v;
      __syncthreads();
    }
    int add = (t < 255) ? aux[t + 1] : 0;
    for (int j = 0; j < 4; ++j) fh[base + j] += add;
    __syncthreads();
    for (int j = 0; j < 4; ++j) {
      int idx = base + j;
      int sv = fh[idx];
      int nx = (idx < 1023) ? fh[idx + 1] : 0;
      if (sv >= r && nx < r) { s_T2 = idx; s_r2 = r - nx; }
    }
  }
  __syncthreads();
  const int T2 = s_T2, r2 = s_r2;
  // pass 2: emit fine>T2; collect fine==T2 ties
  for (int i = t; i < nc; i += 256) {
    unsigned long long e = C[i];
    uint32_t m = (uint32_t)(e >> 32), p = (uint32_t)e;
    if (cbin_of(m) == T) {
      uint32_t f = (m - baseM) >> 4; if (f > 1023u) f = 1023u;
      if ((int)f > T2) {
        int pos = atomicAdd(&s_pos, 1);
        g_pts[img * NSEL + pos] = pack_pt(p);
      } else if ((int)f == T2) {
        int j = atomicAdd(&s_nt, 1);
        if (j < 256) ties[j] = e;
      }
    }
  }
  __syncthreads();
  int nt = s_nt < 256 ? s_nt : 256;
  for (int i = t; i < nt; i += 256) {
    unsigned long long e = ties[i];
    uint32_t mi = (uint32_t)(e >> 32), pi = (uint32_t)e;
    int rank = 0;
    for (int j = 0; j < nt; ++j) {
      unsigned long long e2 = ties[j];
      uint32_t mj = (uint32_t)(e2 >> 32), pj = (uint32_t)e2;
      rank += (mj > mi) || (mj == mi && pj < pi);
    }
    if (rank < r2) {
      int pos = atomicAdd(&s_pos, 1);
      g_pts[img * NSEL + pos] = pack_pt(pi);
    }
  }
  __syncthreads();
  if (t == 0) g_counts[img] = s_pos;  // == min(cv,1000)
}

// ---------------- K5 ----------------
__global__ __launch_bounds__(256) void haus_kernel(
    const uint32_t* __restrict__ g_pts, const int* __restrict__ g_counts,
    float* __restrict__ g_maxd2) {
  const int bid = blockIdx.x;
  const int img = bid >> 3;
  const int dir = (bid >> 2) & 1;
  const int seg = bid & 3;
  const int t = threadIdx.x;
  const int iOwn = dir ? 64 + img : img;
  const int iOth = dir ? img : 64 + img;
  const int nOwn = g_counts[iOwn];
  const int nOth = g_counts[iOth];
  __shared__ float2 o[NSEL];
  __shared__ float red[256];
  for (int i = t; i < nOth; i += 256) {
    uint32_t v = g_pts[iOth * NSEL + i];
    o[i] = make_float2((float)(v >> 16), (float)(v & 0xFFFFu));
  }
  __syncthreads();
  float best = 0.0f;
  const int lo = seg * 250;
  const int hi = min(nOwn, lo + 250);
  for (int i = lo + t; i < hi; i += 256) {
    uint32_t v = g_pts[iOwn * NSEL + i];
    float pr = (float)(v >> 16), pc = (float)(v & 0xFFFFu);
    float mn = 3.4e38f;
    for (int j = 0; j < nOth; ++j) {
      float dr = pr - o[j].x, dc = pc - o[j].y;
      mn = fminf(mn, dr * dr + dc * dc);
    }
    best = fmaxf(best, mn);
  }
  red[t] = best;
  __syncthreads();
  for (int st = 128; st > 0; st >>= 1) {
    if (t < st) red[t] = fmaxf(red[t], red[t + st]);
    __syncthreads();
  }
  if (t == 0) atomicMax((unsigned int*)&g_maxd2[img], __float_as_uint(red[0]));
}

// ---------------- K6 ----------------
__global__ __launch_bounds__(64) void fin_kernel(const float* __restrict__ g_maxd2,
                                                 float* __restrict__ out) {
  const int t = threadIdx.x;
  float diag = sqrtf((float)(HH * HH + WW * WW));
  float hd = sqrtf(fmaxf(g_maxd2[t], 0.0f)) / diag;
  hd = fminf(fmaxf(hd, 0.0f), 0.1f);
  float s = hd;
  for (int o = 32; o > 0; o >>= 1) s += __shfl_down(s, o);
  if (t == 0) out[0] = s * 0.015625f;
}

// ---------------- workspace layout (bytes) ----------------
#define WS_HIST   0u                         // 128*256*4 = 131072
#define WS_CANDC  131072u                    // 512
#define WS_OVF    (WS_CANDC + 512u)          // 512
#define WS_COUNTS (WS_OVF + 512u)            // 512
#define WS_MAXD2  (WS_COUNTS + 512u)         // 256
#define WS_PARAMS (WS_MAXD2 + 256u)          // 2048
#define WS_ZEND   (WS_PARAMS + 2048u)        // zero through here = 134912
#define WS_PTS    WS_ZEND                    // 128*1000*4 = 512000
#define WS_CAND   (WS_PTS + 512000u)         // 128*16384*8 = 16777216 (~17.4 MB total)

extern "C" void kernel_launch(void* const* d_in, const int* in_sizes, int n_in,
                              void* d_out, int out_size, void* d_ws, size_t ws_size,
                              hipStream_t stream) {
  const float* pred = (const float*)d_in[0];
  const float* tgt = (const float*)d_in[1];
  float* out = (float*)d_out;
  char* ws = (char*)d_ws;
  int* g_hist = (int*)(ws + WS_HIST);
  int* g_candc = (int*)(ws + WS_CANDC);
  int* g_ovf = (int*)(ws + WS_OVF);
  int* g_counts = (int*)(ws + WS_COUNTS);
  float* g_maxd2 = (float*)(ws + WS_MAXD2);
  int* g_params = (int*)(ws + WS_PARAMS);
  uint32_t* g_pts = (uint32_t*)(ws + WS_PTS);
  unsigned long long* g_cand = (unsigned long long*)(ws + WS_CAND);

  hipMemsetAsync(d_out, 0, (size_t)out_size * sizeof(float), stream);
  hipMemsetAsync(d_ws, 0, WS_ZEND, stream);
  sobel_cand<<<2048, 256, 0, stream>>>(pred, tgt, g_hist, g_candc, g_ovf, g_cand);
  thresh_kernel<<<128, 256, 0, stream>>>(g_hist, g_ovf, g_candc, g_params);
  repair_kernel<<<2048, 256, 0, stream>>>(pred, tgt, g_params, g_candc, g_cand);
  resolve_kernel<<<128, 256, 0, stream>>>(g_params, g_candc, g_cand, g_pts, g_counts);
  haus_kernel<<<512, 256, 0, stream>>>(g_pts, g_counts, g_maxd2);
  fin_kernel<<<1, 64, 0, stream>>>(g_maxd2, out);
}